// Round 12
// baseline (304.477 us; speedup 1.0000x reference)
//
#include <hip/hip_runtime.h>

#define T_    8
#define H_    28
#define W_    28
#define NSP   6272      // T*H*W
#define NTOKS 6273
#define DIM   192
#define HEADS 2
#define HD    96
#define SCALE_ 0.10206207261596575f   // 96^-0.5
#define INVS_  9.797958971132712f     // sqrt(96)
#define EPS_  1e-5f

#define QT    64
#define KT    64
#define QB3   99                        // ceil(6273/64)
#define NTILES_TOT 99
#define NSPL  4                         // k-split (4 = measured best, R7)
#define KCH   160                       // extended K channels (96 + 64 one-hot)
#define VT_LD 6400                      // padded vbT row length (tokens)
#define NSTRIP 1569                     // 1 cls + 8*28*7 spatial strips (4 x-tokens each)

using bf16x8 = __attribute__((ext_vector_type(8))) short;
using f32x4  = __attribute__((ext_vector_type(4))) float;
typedef unsigned short u16;
typedef unsigned int   u32;

__device__ __forceinline__ u16 f2b(float f) {   // fp32 -> bf16 bits, RNE
    u32 u = __builtin_bit_cast(u32, f);
    u += 0x7fffu + ((u >> 16) & 1u);
    return (u16)(u >> 16);
}
__device__ __forceinline__ float b2f(u16 v) {
    u32 u = ((u32)v) << 16;
    return __builtin_bit_cast(float, u);
}

// async global->LDS 16B: LDS dest is wave-uniform base + lane*16 (m104)
__device__ __forceinline__ void async16(const void* g, void* l) {
    __builtin_amdgcn_global_load_lds(
        (const __attribute__((address_space(1))) u32*)g,
        (__attribute__((address_space(3))) u32*)l, 16, 0, 0);
}

// ------- Kernel 0: fp32 -> bf16 conversion (x, qkv_w, proj_w) + pool-weight transpose -------
__global__ __launch_bounds__(256) void cvt_bf16(
    const float* __restrict__ s0, u16* __restrict__ d0, int n0,
    const float* __restrict__ s1, u16* __restrict__ d1, int n1,
    const float* __restrict__ s2, u16* __restrict__ d2, int n2,
    const float* __restrict__ wq, const float* __restrict__ wk,
    const float* __restrict__ wv, float* __restrict__ wT)
{
    const int nw = 3 * 27 * 96;
    int tot = n0 + n1 + n2 + nw;
    for (int i = blockIdx.x * 256 + threadIdx.x; i < tot; i += gridDim.x * 256) {
        if (i < n0)                 d0[i] = f2b(s0[i]);
        else if (i < n0 + n1)       d1[i - n0] = f2b(s1[i - n0]);
        else if (i < n0 + n1 + n2)  d2[i - n0 - n1] = f2b(s2[i - n0 - n1]);
        else {
            int j = i - n0 - n1 - n2;       // which*2592 + widx*96 + c
            int which = j / 2592, r = j % 2592;
            int widx = r / 96, c = r % 96;
            const float* src = which == 0 ? wq : (which == 1 ? wk : wv);
            wT[j] = src[c * 27 + widx];
        }
    }
}

// ---------------- Kernel 1: OUT[m][n] = sum_k A[m][k]*W[n][k] + bias[n] (MFMA) --------
__global__ __launch_bounds__(256, 3) void gemm_bf16(
    const u16* __restrict__ A, const u16* __restrict__ Wt,
    const float* __restrict__ bias, float* __restrict__ outf,
    u16* __restrict__ outb, int M, int ldo)
{
    __shared__ __align__(16) u16 als[24 * 512];
    __shared__ __align__(16) u16 wls[24 * 512];
    const int m0 = blockIdx.x * 64, n0 = blockIdx.y * 64;
    const int tid  = threadIdx.x;
    const int w    = tid >> 6;
    const int lane = tid & 63;
    const int quad = lane >> 4;
    const int l16  = lane & 15;
    {
        int m = m0 + lane; if (m > M - 1) m = M - 1;
        const u16* ab = A  + (size_t)m * 192;
        const u16* wb = Wt + (size_t)(n0 + lane) * 192;
        #pragma unroll
        for (int i = 0; i < 6; ++i) {
            int g = w * 6 + i;              // 0..23, covers k = g*8..g*8+7
            async16(ab + g * 8, als + g * 512);
            async16(wb + g * 8, wls + g * 512);
        }
    }
    __syncthreads();
    f32x4 acc[4];
    #pragma unroll
    for (int mt = 0; mt < 4; ++mt) acc[mt] = (f32x4){0,0,0,0};
    #pragma unroll
    for (int cc = 0; cc < 6; ++cc) {
        bf16x8 bf = *(const bf16x8*)(wls + (((cc * 4 + quad) * 64) + w * 16 + l16) * 8);
        #pragma unroll
        for (int mt = 0; mt < 4; ++mt) {
            bf16x8 af = *(const bf16x8*)(als + (((cc * 4 + quad) * 64) + mt * 16 + l16) * 8);
            acc[mt] = __builtin_amdgcn_mfma_f32_16x16x32_bf16(af, bf, acc[mt], 0, 0, 0);
        }
    }
    float bj = bias[n0 + w * 16 + l16];
    #pragma unroll
    for (int mt = 0; mt < 4; ++mt) {
        #pragma unroll
        for (int rr = 0; rr < 4; ++rr) {
            int row = m0 + mt * 16 + quad * 4 + rr;
            if (row < M) {
                float v = acc[mt][rr] + bj;
                size_t off = (size_t)row * ldo + n0 + w * 16 + l16;
                if (outb) outb[off] = f2b(v);
                else      outf[off] = v;
            }
        }
    }
}

// ------------- Kernel 2: pool+LN v3 — 4-token x-strips + fused relbias + one-hot ------
__global__ __launch_bounds__(192) void pool_ln3(
    const u16* __restrict__ qkvb, const float* __restrict__ wT,
    const float* __restrict__ gq, const float* __restrict__ bq,
    const float* __restrict__ gk, const float* __restrict__ bk,
    const float* __restrict__ gv, const float* __restrict__ bv,
    const float* __restrict__ rel_h, const float* __restrict__ rel_w,
    const float* __restrict__ rel_t,
    u16* __restrict__ qbb, u16* __restrict__ kx, u16* __restrict__ vbb,
    float* __restrict__ bt, float* __restrict__ bh, float* __restrict__ bw)
{
    __shared__ __align__(16) float qls[4][96];
    const int h   = blockIdx.x / NSTRIP;
    const int s   = blockIdx.x % NSTRIP;
    const int wid  = threadIdx.x / 64;   // which: 0=q 1=k 2=v
    const int lane = threadIdx.x & 63;
    const bool two = (lane < 32);

    const float* gg = wid == 0 ? gq : (wid == 1 ? gk : gv);
    const float* bb = wid == 0 ? bq : (wid == 1 ? bk : bv);
    const float g0 = gg[lane], b0 = bb[lane];
    const float g1 = two ? gg[64 + lane] : 0.f;
    const float b1 = two ? bb[64 + lane] : 0.f;
    const int col0 = wid * DIM + h * HD;

    if (s == 0) {
        float v0 = b2f(qkvb[col0 + lane]);
        float v1 = two ? b2f(qkvb[col0 + 64 + lane]) : 0.f;
        float s1 = v0 + v1, s2 = v0 * v0 + v1 * v1;
        #pragma unroll
        for (int off = 32; off >= 1; off >>= 1) {
            s1 += __shfl_xor(s1, off);
            s2 += __shfl_xor(s2, off);
        }
        float m = s1 * (1.f / HD);
        float inv = rsqrtf(s2 * (1.f / HD) - m * m + EPS_);
        float o0 = (v0 - m) * inv * g0 + b0;
        float o1 = (v1 - m) * inv * g1 + b1;
        size_t off0 = (size_t)h * NTOKS * HD + lane;
        if (wid == 0) {
            qbb[off0] = f2b(o0 * SCALE_);
            if (two) qbb[off0 + 64] = f2b(o1 * SCALE_);
        } else if (wid == 1) {
            size_t kb = (size_t)h * NTOKS * KCH;
            kx[kb + lane] = f2b(o0);
            if (two) kx[kb + 64 + lane] = f2b(o1);
            kx[kb + 96 + lane] = 0;              // cls: no one-hot bias channels
        } else {
            vbb[off0] = f2b(o0);
            if (two) vbb[off0 + 64] = f2b(o1);
        }
        return;
    }

    const int ss = s - 1;
    const int t  = ss / 196;
    const int rm = ss % 196;
    const int y  = rm / 7;
    const int x0 = (rm % 7) * 4;

    const float* wslice = wT + wid * 2592;   // [27][96]
    float v0a[4] = {0,0,0,0}, v1a[4] = {0,0,0,0};

    #pragma unroll
    for (int dt = -1; dt <= 1; ++dt) {
        int tt = t + dt; if (tt < 0 || tt >= T_) continue;
        #pragma unroll
        for (int dy = -1; dy <= 1; ++dy) {
            int yy = y + dy; if (yy < 0 || yy >= H_) continue;
            int wb = (dt + 1) * 9 + (dy + 1) * 3;
            float wa[3], wbh[3];
            #pragma unroll
            for (int o = 0; o < 3; ++o) {
                wa[o]  = wslice[(wb + o) * 96 + lane];
                wbh[o] = two ? wslice[(wb + o) * 96 + 64 + lane] : 0.f;
            }
            int rowbase = 1 + (tt * H_ + yy) * W_;
            #pragma unroll
            for (int i = 0; i < 6; ++i) {
                int xp = x0 - 1 + i;
                float r0 = 0.f, r1 = 0.f;
                if (xp >= 0 && xp < W_) {
                    const u16* bp = qkvb + (size_t)(rowbase + xp) * 576 + col0;
                    r0 = b2f(bp[lane]);
                    if (two) r1 = b2f(bp[64 + lane]);
                }
                #pragma unroll
                for (int j = 0; j < 4; ++j) {
                    int o = i - j;
                    if (o >= 0 && o <= 2) {
                        v0a[j] += wa[o] * r0;
                        v1a[j] += wbh[o] * r1;
                    }
                }
            }
        }
    }

    #pragma unroll
    for (int j = 0; j < 4; ++j) {
        float s1 = v0a[j] + v1a[j];
        float s2 = v0a[j] * v0a[j] + v1a[j] * v1a[j];
        #pragma unroll
        for (int off = 32; off >= 1; off >>= 1) {
            s1 += __shfl_xor(s1, off);
            s2 += __shfl_xor(s2, off);
        }
        float m = s1 * (1.f / HD);
        float inv = rsqrtf(s2 * (1.f / HD) - m * m + EPS_);
        float o0 = (v0a[j] - m) * inv * g0 + b0;
        float o1 = (v1a[j] - m) * inv * g1 + b1;
        int xj  = x0 + j;
        int tok = 1 + (t * H_ + y) * W_ + xj;
        size_t off0 = ((size_t)h * NTOKS + tok) * HD + lane;
        if (wid == 0) {
            qbb[off0] = f2b(o0 * SCALE_);
            qls[j][lane] = o0;
            if (two) { qbb[off0 + 64] = f2b(o1 * SCALE_); qls[j][64 + lane] = o1; }
        } else if (wid == 1) {
            size_t kb = ((size_t)h * NTOKS + tok) * KCH;
            kx[kb + lane] = f2b(o0);
            if (two) kx[kb + 64 + lane] = f2b(o1);
            // one-hot bias channels (96..159): kt=t, kh=y, kw=xj
            int match = (lane < 8) ? (lane == t) : (lane < 36) ? (lane - 8 == y) : (lane - 36 == xj);
            kx[kb + 96 + lane] = match ? (u16)0x3F80 : (u16)0;
        } else {
            vbb[off0] = f2b(o0);
            if (two) vbb[off0 + 64] = f2b(o1);
        }
    }

    if (threadIdx.x < 64) {
        int tq = threadIdx.x;
        #pragma unroll
        for (int j = 0; j < 4; ++j) {
            int sp = (t * H_ + y) * W_ + x0 + j;   // tok-1
            const float* row;
            float* outp;
            if (tq < 8)       { row = rel_t + (size_t)(t - tq        + (T_ - 1)) * HD; outp = bt + ((size_t)h*NSP + sp)*8  + tq;      }
            else if (tq < 36) { row = rel_h + (size_t)(y - (tq - 8)  + (H_ - 1)) * HD; outp = bh + ((size_t)h*NSP + sp)*28 + (tq-8);  }
            else              { row = rel_w + (size_t)(x0 + j - (tq - 36) + (W_ - 1)) * HD; outp = bw + ((size_t)h*NSP + sp)*28 + (tq-36); }
            const float4* r4 = (const float4*)row;
            const float4* q4 = (const float4*)qls[j];
            float acc = 0.f;
            #pragma unroll
            for (int i = 0; i < 24; ++i) {
                float4 a = q4[i], b = r4[i];
                acc += a.x*b.x + a.y*b.y + a.z*b.z + a.w*b.w;
            }
            *outp = acc;
        }
    }
}

// ------------- Kernel 2b: transpose V to [h][c][tok] (one-hot moved to pool_ln3) ------
__global__ __launch_bounds__(256) void vtrans(
    const u16* __restrict__ vbb, u16* __restrict__ vbT)
{
    __shared__ u16 tls[128][104];
    int h  = blockIdx.y;
    int t0 = blockIdx.x * 128;
    int tid = threadIdx.x;
    #pragma unroll
    for (int it = 0; it < 24; ++it) {           // 128*48 dwords
        int idx = tid + it * 256;
        int row = idx / 48, col = idx % 48;
        int tok = t0 + row; if (tok > NTOKS - 1) tok = NTOKS - 1;
        *(u32*)&tls[row][col*2] = *(const u32*)(vbb + ((size_t)h * NTOKS + tok) * HD + col*2);
    }
    __syncthreads();
    #pragma unroll
    for (int it = 0; it < 24; ++it) {           // 96*64 dwords
        int idx = tid + it * 256;
        int c = idx / 64, tp = idx % 64;
        u32 lo = tls[tp*2][c], hi = tls[tp*2+1][c];
        *(u32*)(vbT + ((size_t)h * HD + c) * VT_LD + t0 + tp*2) = lo | (hi << 16);
    }
}

// ------------- Kernel 4: MFMA flash attention v4 (R10-exact, NSPL=4, bf16 pO) ------
__global__ __launch_bounds__(256, 2) void attn_mfma4(
    const u16* __restrict__ qbb, const u16* __restrict__ kx,
    const u16* __restrict__ vbT,
    const float* __restrict__ btp, const float* __restrict__ bhp,
    const float* __restrict__ bwp,
    u16* __restrict__ pO, float* __restrict__ pl)
{
    __shared__ __align__(16) u16 kls[2][20 * 512];  // 40 KB
    __shared__ __align__(16) u16 vls[2][12 * 512];  // 24 KB
    __shared__ __align__(16) u16 pls[64 * 72];      //  9 KB

    const int g     = blockIdx.x & 7;
    const int qb    = blockIdx.x >> 3;
    const int h     = g >> 2;
    const int split = g & 3;
    const int q0    = qb * QT;
    const int tid   = threadIdx.x;
    const int w     = tid >> 6;
    const int lane  = tid & 63;
    const int quad  = lane >> 4;
    const int l16   = lane & 15;

    const int t0 = split * 25;
    const int t1 = (t0 + 25 < NTILES_TOT) ? t0 + 25 : NTILES_TOT;

    auto stage = [&](int buf, int tile) {
        int kb0 = tile * KT;
        int key = kb0 + lane; if (key > NTOKS - 1) key = NTOKS - 1;
        const u16* gbase = kx + ((size_t)h * NTOKS + key) * KCH;
        #pragma unroll
        for (int i = 0; i < 5; ++i) {
            int CH = w * 5 + i;
            int c5 = CH >> 2, qd = CH & 3;
            async16(gbase + c5 * 32 + qd * 8, kls[buf] + CH * 512);
        }
        #pragma unroll
        for (int i = 0; i < 3; ++i) {
            int CH2 = w * 3 + i;
            int E = CH2 * 64 + lane;
            int kcq = E / 96, n = E - kcq * 96;
            int kc = kcq >> 2, qd = kcq & 3;
            const u16* src = vbT + ((size_t)h * HD + n) * VT_LD + kb0 + kc * 32 + qd * 8;
            async16(src, vls[buf] + CH2 * 512);
        }
    };

    stage(0, t0);

    bf16x8 aq[5];
    {
        int tokc = q0 + w * 16 + l16;
        int tq = tokc > NTOKS - 1 ? NTOKS - 1 : tokc;
        const u16* qrow = qbb + ((size_t)h * NTOKS + tq) * HD;
        #pragma unroll
        for (int cc = 0; cc < 3; ++cc)
            aq[cc] = *(const bf16x8*)(qrow + cc * 32 + quad * 8);
        bool has = (tokc >= 1 && tokc < NTOKS);
        int sp = tokc - 1;
        #pragma unroll
        for (int cc = 3; cc < 5; ++cc) {
            bf16x8 tf;
            #pragma unroll
            for (int j = 0; j < 8; ++j) {
                int kk = (cc - 3) * 32 + quad * 8 + j;
                float v = 0.f;
                if (has) {
                    if (kk < 8)       v = btp[((size_t)h * NSP + sp) * 8  + kk];
                    else if (kk < 36) v = bhp[((size_t)h * NSP + sp) * 28 + (kk - 8)];
                    else              v = bwp[((size_t)h * NSP + sp) * 28 + (kk - 36)];
                }
                tf[j] = (short)f2b(v);
            }
            aq[cc] = tf;
        }
    }

    f32x4 accO[6];
    #pragma unroll
    for (int nt = 0; nt < 6; ++nt) accO[nt] = (f32x4){0,0,0,0};
    float psum[4] = {0.f, 0.f, 0.f, 0.f};

    for (int tile = t0; tile < t1; ++tile) {
        const int cur = (tile - t0) & 1;
        __syncthreads();
        if (tile + 1 < t1) stage(cur ^ 1, tile + 1);
        const int kb0 = tile * KT;
        const u16* kcur = kls[cur];
        const u16* vcur = vls[cur];
        f32x4 sacc[4];
        #pragma unroll
        for (int nt = 0; nt < 4; ++nt) sacc[nt] = (f32x4){0,0,0,0};
        #pragma unroll
        for (int cc = 0; cc < 5; ++cc) {
            #pragma unroll
            for (int nt = 0; nt < 4; ++nt) {
                bf16x8 bk = *(const bf16x8*)(kcur + (((cc * 4 + quad) * 64) + nt * 16 + l16) * 8);
                sacc[nt] = __builtin_amdgcn_mfma_f32_16x16x32_bf16(aq[cc], bk, sacc[nt], 0, 0, 0);
            }
        }
        #pragma unroll
        for (int nt = 0; nt < 4; ++nt) {
            int keyg = kb0 + nt * 16 + l16;
            bool ok = keyg < NTOKS;
            #pragma unroll
            for (int rr = 0; rr < 4; ++rr) {
                float p = ok ? __expf(sacc[nt][rr]) : 0.f;
                psum[rr] += p;
                pls[(w * 16 + quad * 4 + rr) * 72 + nt * 16 + l16] = f2b(p);
            }
        }
        #pragma unroll
        for (int kc = 0; kc < 2; ++kc) {
            bf16x8 ap = *(const bf16x8*)(pls + (w * 16 + l16) * 72 + kc * 32 + quad * 8);
            #pragma unroll
            for (int nt = 0; nt < 6; ++nt) {
                bf16x8 bv = *(const bf16x8*)(vcur + (((kc * 4 + quad) * 96) + nt * 16 + l16) * 8);
                accO[nt] = __builtin_amdgcn_mfma_f32_16x16x32_bf16(ap, bv, accO[nt], 0, 0, 0);
            }
        }
    }

    #pragma unroll
    for (int off = 1; off < 16; off <<= 1) {
        #pragma unroll
        for (int rr = 0; rr < 4; ++rr)
            psum[rr] += __shfl_xor(psum[rr], off);
    }
    const int sh = split * HEADS + h;
    if (l16 == 0) {
        #pragma unroll
        for (int rr = 0; rr < 4; ++rr) {
            int tok = q0 + w * 16 + quad * 4 + rr;
            if (tok < NTOKS)
                pl[(size_t)sh * NTOKS + tok] = psum[rr];
        }
    }
    #pragma unroll
    for (int rr = 0; rr < 4; ++rr) {
        int tok = q0 + w * 16 + quad * 4 + rr;
        if (tok >= NTOKS) continue;
        #pragma unroll
        for (int nt = 0; nt < 6; ++nt)
            pO[((size_t)sh * NTOKS + tok) * HD + nt * 16 + l16] = f2b(accO[nt][rr]);
    }
}

// ------- Kernel 5: fused combine + residual + proj GEMM -------
// grid = (QB3, 3). A-staging computes pre[64 rows][192 ch] from pO/pl/qbb into als.
__global__ __launch_bounds__(256, 3) void proj_fused(
    const u16* __restrict__ pO, const float* __restrict__ pl,
    const u16* __restrict__ qbb, const u16* __restrict__ Wt,
    const float* __restrict__ bias, float* __restrict__ out)
{
    __shared__ __align__(16) u16 als[24 * 512];
    __shared__ __align__(16) u16 wls[24 * 512];
    const int m0 = blockIdx.x * 64, n0 = blockIdx.y * 64;
    const int tid  = threadIdx.x;
    const int w    = tid >> 6;
    const int lane = tid & 63;
    const int quad = lane >> 4;
    const int l16  = lane & 15;

    // W staging (async16, 6 per wave)
    {
        const u16* wb = Wt + (size_t)(n0 + lane) * 192;
        #pragma unroll
        for (int i = 0; i < 6; ++i) {
            int g = w * 6 + i;
            async16(wb + g * 8, wls + g * 512);
        }
    }
    // A staging: fused combine (24 channel-pairs per thread)
    #pragma unroll
    for (int it = 0; it < 24; ++it) {
        int i = tid + it * 256;                 // 0..6143 : r*96 + dp
        int r  = i / 96, dp = i - r * 96;
        int d0 = dp * 2;
        int hh = d0 / HD, c0 = d0 - hh * HD;
        int tok = m0 + r; if (tok > NTOKS - 1) tok = NTOKS - 1;
        float l = 0.f, o0 = 0.f, o1 = 0.f;
        #pragma unroll
        for (int s = 0; s < NSPL; ++s) {
            l += pl[(size_t)(s * HEADS + hh) * NTOKS + tok];
            u32 pr = *(const u32*)(pO + ((size_t)(s * HEADS + hh) * NTOKS + tok) * HD + c0);
            o0 += b2f((u16)(pr & 0xffffu));
            o1 += b2f((u16)(pr >> 16));
        }
        float v0 = o0 / l, v1 = o1 / l;
        if (tok >= 1) {
            u32 qr = *(const u32*)(qbb + ((size_t)hh * NTOKS + tok) * HD + c0);
            v0 += b2f((u16)(qr & 0xffffu)) * INVS_;
            v1 += b2f((u16)(qr >> 16)) * INVS_;
        }
        // chunk layout: als[g*512 + r*8 + (d0%8)], g = d0/8
        int gch = d0 >> 3;
        *(u32*)(als + gch * 512 + r * 8 + (d0 & 7)) = (u32)f2b(v0) | ((u32)f2b(v1) << 16);
    }
    __syncthreads();

    f32x4 acc[4];
    #pragma unroll
    for (int mt = 0; mt < 4; ++mt) acc[mt] = (f32x4){0,0,0,0};
    #pragma unroll
    for (int cc = 0; cc < 6; ++cc) {
        bf16x8 bf = *(const bf16x8*)(wls + (((cc * 4 + quad) * 64) + w * 16 + l16) * 8);
        #pragma unroll
        for (int mt = 0; mt < 4; ++mt) {
            bf16x8 af = *(const bf16x8*)(als + (((cc * 4 + quad) * 64) + mt * 16 + l16) * 8);
            acc[mt] = __builtin_amdgcn_mfma_f32_16x16x32_bf16(af, bf, acc[mt], 0, 0, 0);
        }
    }
    float bj = bias[n0 + w * 16 + l16];
    #pragma unroll
    for (int mt = 0; mt < 4; ++mt) {
        #pragma unroll
        for (int rr = 0; rr < 4; ++rr) {
            int row = m0 + mt * 16 + quad * 4 + rr;
            if (row < NTOKS)
                out[(size_t)row * DIM + n0 + w * 16 + l16] = acc[mt][rr] + bj;
        }
    }
}

extern "C" void kernel_launch(void* const* d_in, const int* in_sizes, int n_in,
                              void* d_out, int out_size, void* d_ws, size_t ws_size,
                              hipStream_t stream) {
    (void)in_sizes; (void)n_in; (void)out_size; (void)ws_size;
    const float* x      = (const float*)d_in[0];
    const float* qkv_w  = (const float*)d_in[1];
    const float* qkv_b  = (const float*)d_in[2];
    const float* proj_w = (const float*)d_in[3];
    const float* proj_b = (const float*)d_in[4];
    const float* pool_q = (const float*)d_in[5];
    const float* pool_k = (const float*)d_in[6];
    const float* pool_v = (const float*)d_in[7];
    const float* gq     = (const float*)d_in[8];
    const float* bq     = (const float*)d_in[9];
    const float* gk     = (const float*)d_in[10];
    const float* bk     = (const float*)d_in[11];
    const float* gv     = (const float*)d_in[12];
    const float* bv     = (const float*)d_in[13];
    const float* rel_h  = (const float*)d_in[14];
    const float* rel_w  = (const float*)d_in[15];
    const float* rel_t  = (const float*)d_in[16];

    char* p = (char*)d_ws;
    auto alloc = [&](size_t bytes) -> void* {
        void* r = (void*)p; p += (bytes + 255) & ~(size_t)255; return r;
    };
    u16*   qkvb = (u16*) alloc((size_t)NTOKS * 576 * 2);
    u16*   qbb = (u16*)  alloc((size_t)HEADS * NTOKS * HD * 2);
    u16*   kxb = (u16*)  alloc((size_t)HEADS * NTOKS * KCH * 2);
    u16*   vbb = (u16*)  alloc((size_t)HEADS * NTOKS * HD * 2);
    u16*   vbT = (u16*)  alloc((size_t)HEADS * HD * VT_LD * 2);
    float* bt  = (float*)alloc((size_t)HEADS * NSP * 8 * 4);
    float* bh  = (float*)alloc((size_t)HEADS * NSP * 28 * 4);
    float* bw  = (float*)alloc((size_t)HEADS * NSP * 28 * 4);
    u16*   pO  = (u16*)  alloc((size_t)NSPL * HEADS * NTOKS * HD * 2);
    float* pl  = (float*)alloc((size_t)NSPL * HEADS * NTOKS * 4);
    u16*   xb  = (u16*)  alloc((size_t)NTOKS * DIM * 2);
    u16*   qwb = (u16*)  alloc((size_t)576 * DIM * 2);
    u16*   pwb = (u16*)  alloc((size_t)DIM * DIM * 2);
    float* wT  = (float*)alloc((size_t)3 * 27 * 96 * 4);

    const int nx = NTOKS * DIM, nqw = 576 * DIM, npw = DIM * DIM;
    cvt_bf16<<<1024, 256, 0, stream>>>(x, xb, nx, qkv_w, qwb, nqw, proj_w, pwb, npw,
                                       pool_q, pool_k, pool_v, wT);
    gemm_bf16<<<dim3(QB3, 9), 256, 0, stream>>>(xb, qwb, qkv_b, nullptr, qkvb, NTOKS, 576);
    pool_ln3<<<HEADS * NSTRIP, 192, 0, stream>>>(
        qkvb, wT, gq, bq, gk, bk, gv, bv,
        rel_h, rel_w, rel_t, qbb, kxb, vbb, bt, bh, bw);
    vtrans<<<dim3((NTOKS + 127) / 128, HEADS), 256, 0, stream>>>(vbb, vbT);
    attn_mfma4<<<QB3 * 8, 256, 0, stream>>>(qbb, kxb, vbT, bt, bh, bw, pO, pl);
    proj_fused<<<dim3(QB3, 3), 256, 0, stream>>>(pO, pl, qbb, pwb, proj_b, (float*)d_out);
}

// Round 13
// 293.554 us; speedup vs baseline: 1.0372x; 1.0372x over previous
//
#include <hip/hip_runtime.h>

#define T_    8
#define H_    28
#define W_    28
#define NSP   6272      // T*H*W
#define NTOKS 6273
#define DIM   192
#define HEADS 2
#define HD    96
#define SCALE_ 0.10206207261596575f   // 96^-0.5
#define INVS_  9.797958971132712f     // sqrt(96)
#define EPS_  1e-5f

#define QT    64
#define KT    64
#define QB3   99                        // ceil(6273/64)
#define NTILES_TOT 99
#define NSPL  4                         // k-split (4 = measured best, R7)
#define KCH   160                       // extended K channels (96 + 64 one-hot)
#define VT_LD 6400                      // padded vbT row length (tokens)
#define NSTRIP 1569                     // 1 cls + 8*28*7 spatial strips (4 x-tokens each)

using bf16x8 = __attribute__((ext_vector_type(8))) short;
using f32x4  = __attribute__((ext_vector_type(4))) float;
typedef unsigned short u16;
typedef unsigned int   u32;

__device__ __forceinline__ u16 f2b(float f) {   // fp32 -> bf16 bits, RNE
    u32 u = __builtin_bit_cast(u32, f);
    u += 0x7fffu + ((u >> 16) & 1u);
    return (u16)(u >> 16);
}
__device__ __forceinline__ float b2f(u16 v) {
    u32 u = ((u32)v) << 16;
    return __builtin_bit_cast(float, u);
}

// async global->LDS 16B: LDS dest is wave-uniform base + lane*16 (m104)
__device__ __forceinline__ void async16(const void* g, void* l) {
    __builtin_amdgcn_global_load_lds(
        (const __attribute__((address_space(1))) u32*)g,
        (__attribute__((address_space(3))) u32*)l, 16, 0, 0);
}

// ------- Kernel 0: fp32 -> bf16 conversion (x, qkv_w, proj_w) + pool-weight transpose -------
__global__ __launch_bounds__(256) void cvt_bf16(
    const float* __restrict__ s0, u16* __restrict__ d0, int n0,
    const float* __restrict__ s1, u16* __restrict__ d1, int n1,
    const float* __restrict__ s2, u16* __restrict__ d2, int n2,
    const float* __restrict__ wq, const float* __restrict__ wk,
    const float* __restrict__ wv, float* __restrict__ wT)
{
    const int nw = 3 * 27 * 96;
    int tot = n0 + n1 + n2 + nw;
    for (int i = blockIdx.x * 256 + threadIdx.x; i < tot; i += gridDim.x * 256) {
        if (i < n0)                 d0[i] = f2b(s0[i]);
        else if (i < n0 + n1)       d1[i - n0] = f2b(s1[i - n0]);
        else if (i < n0 + n1 + n2)  d2[i - n0 - n1] = f2b(s2[i - n0 - n1]);
        else {
            int j = i - n0 - n1 - n2;       // which*2592 + widx*96 + c
            int which = j / 2592, r = j % 2592;
            int widx = r / 96, c = r % 96;
            const float* src = which == 0 ? wq : (which == 1 ? wk : wv);
            wT[j] = src[c * 27 + widx];
        }
    }
}

// ---------------- Kernel 1: OUT[m][n] = sum_k A[m][k]*W[n][k] + bias[n] (MFMA) --------
__global__ __launch_bounds__(256, 3) void gemm_bf16(
    const u16* __restrict__ A, const u16* __restrict__ Wt,
    const float* __restrict__ bias, float* __restrict__ outf,
    u16* __restrict__ outb, int M, int ldo)
{
    __shared__ __align__(16) u16 als[24 * 512];
    __shared__ __align__(16) u16 wls[24 * 512];
    const int m0 = blockIdx.x * 64, n0 = blockIdx.y * 64;
    const int tid  = threadIdx.x;
    const int w    = tid >> 6;
    const int lane = tid & 63;
    const int quad = lane >> 4;
    const int l16  = lane & 15;
    {
        int m = m0 + lane; if (m > M - 1) m = M - 1;
        const u16* ab = A  + (size_t)m * 192;
        const u16* wb = Wt + (size_t)(n0 + lane) * 192;
        #pragma unroll
        for (int i = 0; i < 6; ++i) {
            int g = w * 6 + i;              // 0..23, covers k = g*8..g*8+7
            async16(ab + g * 8, als + g * 512);
            async16(wb + g * 8, wls + g * 512);
        }
    }
    __syncthreads();
    f32x4 acc[4];
    #pragma unroll
    for (int mt = 0; mt < 4; ++mt) acc[mt] = (f32x4){0,0,0,0};
    #pragma unroll
    for (int cc = 0; cc < 6; ++cc) {
        bf16x8 bf = *(const bf16x8*)(wls + (((cc * 4 + quad) * 64) + w * 16 + l16) * 8);
        #pragma unroll
        for (int mt = 0; mt < 4; ++mt) {
            bf16x8 af = *(const bf16x8*)(als + (((cc * 4 + quad) * 64) + mt * 16 + l16) * 8);
            acc[mt] = __builtin_amdgcn_mfma_f32_16x16x32_bf16(af, bf, acc[mt], 0, 0, 0);
        }
    }
    float bj = bias[n0 + w * 16 + l16];
    #pragma unroll
    for (int mt = 0; mt < 4; ++mt) {
        #pragma unroll
        for (int rr = 0; rr < 4; ++rr) {
            int row = m0 + mt * 16 + quad * 4 + rr;
            if (row < M) {
                float v = acc[mt][rr] + bj;
                size_t off = (size_t)row * ldo + n0 + w * 16 + l16;
                if (outb) outb[off] = f2b(v);
                else      outf[off] = v;
            }
        }
    }
}

// ------------- Kernel 2: pool+LN v3 — 4-token x-strips + fused relbias + one-hot ------
__global__ __launch_bounds__(192) void pool_ln3(
    const u16* __restrict__ qkvb, const float* __restrict__ wT,
    const float* __restrict__ gq, const float* __restrict__ bq,
    const float* __restrict__ gk, const float* __restrict__ bk,
    const float* __restrict__ gv, const float* __restrict__ bv,
    const float* __restrict__ rel_h, const float* __restrict__ rel_w,
    const float* __restrict__ rel_t,
    u16* __restrict__ qbb, u16* __restrict__ kx, u16* __restrict__ vbb,
    float* __restrict__ bt, float* __restrict__ bh, float* __restrict__ bw)
{
    __shared__ __align__(16) float qls[4][96];
    const int h   = blockIdx.x / NSTRIP;
    const int s   = blockIdx.x % NSTRIP;
    const int wid  = threadIdx.x / 64;   // which: 0=q 1=k 2=v
    const int lane = threadIdx.x & 63;
    const bool two = (lane < 32);

    const float* gg = wid == 0 ? gq : (wid == 1 ? gk : gv);
    const float* bb = wid == 0 ? bq : (wid == 1 ? bk : bv);
    const float g0 = gg[lane], b0 = bb[lane];
    const float g1 = two ? gg[64 + lane] : 0.f;
    const float b1 = two ? bb[64 + lane] : 0.f;
    const int col0 = wid * DIM + h * HD;

    if (s == 0) {
        float v0 = b2f(qkvb[col0 + lane]);
        float v1 = two ? b2f(qkvb[col0 + 64 + lane]) : 0.f;
        float s1 = v0 + v1, s2 = v0 * v0 + v1 * v1;
        #pragma unroll
        for (int off = 32; off >= 1; off >>= 1) {
            s1 += __shfl_xor(s1, off);
            s2 += __shfl_xor(s2, off);
        }
        float m = s1 * (1.f / HD);
        float inv = rsqrtf(s2 * (1.f / HD) - m * m + EPS_);
        float o0 = (v0 - m) * inv * g0 + b0;
        float o1 = (v1 - m) * inv * g1 + b1;
        size_t off0 = (size_t)h * NTOKS * HD + lane;
        if (wid == 0) {
            qbb[off0] = f2b(o0 * SCALE_);
            if (two) qbb[off0 + 64] = f2b(o1 * SCALE_);
        } else if (wid == 1) {
            size_t kb = (size_t)h * NTOKS * KCH;
            kx[kb + lane] = f2b(o0);
            if (two) kx[kb + 64 + lane] = f2b(o1);
            kx[kb + 96 + lane] = 0;              // cls: no one-hot bias channels
        } else {
            vbb[off0] = f2b(o0);
            if (two) vbb[off0 + 64] = f2b(o1);
        }
        return;
    }

    const int ss = s - 1;
    const int t  = ss / 196;
    const int rm = ss % 196;
    const int y  = rm / 7;
    const int x0 = (rm % 7) * 4;

    const float* wslice = wT + wid * 2592;   // [27][96]
    float v0a[4] = {0,0,0,0}, v1a[4] = {0,0,0,0};

    #pragma unroll
    for (int dt = -1; dt <= 1; ++dt) {
        int tt = t + dt; if (tt < 0 || tt >= T_) continue;
        #pragma unroll
        for (int dy = -1; dy <= 1; ++dy) {
            int yy = y + dy; if (yy < 0 || yy >= H_) continue;
            int wb = (dt + 1) * 9 + (dy + 1) * 3;
            float wa[3], wbh[3];
            #pragma unroll
            for (int o = 0; o < 3; ++o) {
                wa[o]  = wslice[(wb + o) * 96 + lane];
                wbh[o] = two ? wslice[(wb + o) * 96 + 64 + lane] : 0.f;
            }
            int rowbase = 1 + (tt * H_ + yy) * W_;
            #pragma unroll
            for (int i = 0; i < 6; ++i) {
                int xp = x0 - 1 + i;
                float r0 = 0.f, r1 = 0.f;
                if (xp >= 0 && xp < W_) {
                    const u16* bp = qkvb + (size_t)(rowbase + xp) * 576 + col0;
                    r0 = b2f(bp[lane]);
                    if (two) r1 = b2f(bp[64 + lane]);
                }
                #pragma unroll
                for (int j = 0; j < 4; ++j) {
                    int o = i - j;
                    if (o >= 0 && o <= 2) {
                        v0a[j] += wa[o] * r0;
                        v1a[j] += wbh[o] * r1;
                    }
                }
            }
        }
    }

    #pragma unroll
    for (int j = 0; j < 4; ++j) {
        float s1 = v0a[j] + v1a[j];
        float s2 = v0a[j] * v0a[j] + v1a[j] * v1a[j];
        #pragma unroll
        for (int off = 32; off >= 1; off >>= 1) {
            s1 += __shfl_xor(s1, off);
            s2 += __shfl_xor(s2, off);
        }
        float m = s1 * (1.f / HD);
        float inv = rsqrtf(s2 * (1.f / HD) - m * m + EPS_);
        float o0 = (v0a[j] - m) * inv * g0 + b0;
        float o1 = (v1a[j] - m) * inv * g1 + b1;
        int xj  = x0 + j;
        int tok = 1 + (t * H_ + y) * W_ + xj;
        size_t off0 = ((size_t)h * NTOKS + tok) * HD + lane;
        if (wid == 0) {
            qbb[off0] = f2b(o0 * SCALE_);
            qls[j][lane] = o0;
            if (two) { qbb[off0 + 64] = f2b(o1 * SCALE_); qls[j][64 + lane] = o1; }
        } else if (wid == 1) {
            size_t kb = ((size_t)h * NTOKS + tok) * KCH;
            kx[kb + lane] = f2b(o0);
            if (two) kx[kb + 64 + lane] = f2b(o1);
            // one-hot bias channels (96..159): kt=t, kh=y, kw=xj
            int match = (lane < 8) ? (lane == t) : (lane < 36) ? (lane - 8 == y) : (lane - 36 == xj);
            kx[kb + 96 + lane] = match ? (u16)0x3F80 : (u16)0;
        } else {
            vbb[off0] = f2b(o0);
            if (two) vbb[off0 + 64] = f2b(o1);
        }
    }

    if (threadIdx.x < 64) {
        int tq = threadIdx.x;
        #pragma unroll
        for (int j = 0; j < 4; ++j) {
            int sp = (t * H_ + y) * W_ + x0 + j;   // tok-1
            const float* row;
            float* outp;
            if (tq < 8)       { row = rel_t + (size_t)(t - tq        + (T_ - 1)) * HD; outp = bt + ((size_t)h*NSP + sp)*8  + tq;      }
            else if (tq < 36) { row = rel_h + (size_t)(y - (tq - 8)  + (H_ - 1)) * HD; outp = bh + ((size_t)h*NSP + sp)*28 + (tq-8);  }
            else              { row = rel_w + (size_t)(x0 + j - (tq - 36) + (W_ - 1)) * HD; outp = bw + ((size_t)h*NSP + sp)*28 + (tq-36); }
            const float4* r4 = (const float4*)row;
            const float4* q4 = (const float4*)qls[j];
            float acc = 0.f;
            #pragma unroll
            for (int i = 0; i < 24; ++i) {
                float4 a = q4[i], b = r4[i];
                acc += a.x*b.x + a.y*b.y + a.z*b.z + a.w*b.w;
            }
            *outp = acc;
        }
    }
}

// ------------- Kernel 2b: transpose V to [h][c][tok] (one-hot lives in pool_ln3) ------
__global__ __launch_bounds__(256) void vtrans(
    const u16* __restrict__ vbb, u16* __restrict__ vbT)
{
    __shared__ u16 tls[128][104];
    int h  = blockIdx.y;
    int t0 = blockIdx.x * 128;
    int tid = threadIdx.x;
    #pragma unroll
    for (int it = 0; it < 24; ++it) {           // 128*48 dwords
        int idx = tid + it * 256;
        int row = idx / 48, col = idx % 48;
        int tok = t0 + row; if (tok > NTOKS - 1) tok = NTOKS - 1;
        *(u32*)&tls[row][col*2] = *(const u32*)(vbb + ((size_t)h * NTOKS + tok) * HD + col*2);
    }
    __syncthreads();
    #pragma unroll
    for (int it = 0; it < 24; ++it) {           // 96*64 dwords
        int idx = tid + it * 256;
        int c = idx / 64, tp = idx % 64;
        u32 lo = tls[tp*2][c], hi = tls[tp*2+1][c];
        *(u32*)(vbT + ((size_t)h * HD + c) * VT_LD + t0 + tp*2) = lo | (hi << 16);
    }
}

// ------------- Kernel 4: MFMA flash attention v4 (R10-exact, NSPL=4, bf16 pO) ------
__global__ __launch_bounds__(256, 2) void attn_mfma4(
    const u16* __restrict__ qbb, const u16* __restrict__ kx,
    const u16* __restrict__ vbT,
    const float* __restrict__ btp, const float* __restrict__ bhp,
    const float* __restrict__ bwp,
    u16* __restrict__ pO, float* __restrict__ pl)
{
    __shared__ __align__(16) u16 kls[2][20 * 512];  // 40 KB
    __shared__ __align__(16) u16 vls[2][12 * 512];  // 24 KB
    __shared__ __align__(16) u16 pls[64 * 72];      //  9 KB

    const int g     = blockIdx.x & 7;
    const int qb    = blockIdx.x >> 3;
    const int h     = g >> 2;
    const int split = g & 3;
    const int q0    = qb * QT;
    const int tid   = threadIdx.x;
    const int w     = tid >> 6;
    const int lane  = tid & 63;
    const int quad  = lane >> 4;
    const int l16   = lane & 15;

    const int t0 = split * 25;
    const int t1 = (t0 + 25 < NTILES_TOT) ? t0 + 25 : NTILES_TOT;

    auto stage = [&](int buf, int tile) {
        int kb0 = tile * KT;
        int key = kb0 + lane; if (key > NTOKS - 1) key = NTOKS - 1;
        const u16* gbase = kx + ((size_t)h * NTOKS + key) * KCH;
        #pragma unroll
        for (int i = 0; i < 5; ++i) {
            int CH = w * 5 + i;
            int c5 = CH >> 2, qd = CH & 3;
            async16(gbase + c5 * 32 + qd * 8, kls[buf] + CH * 512);
        }
        #pragma unroll
        for (int i = 0; i < 3; ++i) {
            int CH2 = w * 3 + i;
            int E = CH2 * 64 + lane;
            int kcq = E / 96, n = E - kcq * 96;
            int kc = kcq >> 2, qd = kcq & 3;
            const u16* src = vbT + ((size_t)h * HD + n) * VT_LD + kb0 + kc * 32 + qd * 8;
            async16(src, vls[buf] + CH2 * 512);
        }
    };

    stage(0, t0);

    bf16x8 aq[5];
    {
        int tokc = q0 + w * 16 + l16;
        int tq = tokc > NTOKS - 1 ? NTOKS - 1 : tokc;
        const u16* qrow = qbb + ((size_t)h * NTOKS + tq) * HD;
        #pragma unroll
        for (int cc = 0; cc < 3; ++cc)
            aq[cc] = *(const bf16x8*)(qrow + cc * 32 + quad * 8);
        bool has = (tokc >= 1 && tokc < NTOKS);
        int sp = tokc - 1;
        #pragma unroll
        for (int cc = 3; cc < 5; ++cc) {
            bf16x8 tf;
            #pragma unroll
            for (int j = 0; j < 8; ++j) {
                int kk = (cc - 3) * 32 + quad * 8 + j;
                float v = 0.f;
                if (has) {
                    if (kk < 8)       v = btp[((size_t)h * NSP + sp) * 8  + kk];
                    else if (kk < 36) v = bhp[((size_t)h * NSP + sp) * 28 + (kk - 8)];
                    else              v = bwp[((size_t)h * NSP + sp) * 28 + (kk - 36)];
                }
                tf[j] = (short)f2b(v);
            }
            aq[cc] = tf;
        }
    }

    f32x4 accO[6];
    #pragma unroll
    for (int nt = 0; nt < 6; ++nt) accO[nt] = (f32x4){0,0,0,0};
    float psum[4] = {0.f, 0.f, 0.f, 0.f};

    for (int tile = t0; tile < t1; ++tile) {
        const int cur = (tile - t0) & 1;
        __syncthreads();
        if (tile + 1 < t1) stage(cur ^ 1, tile + 1);
        const int kb0 = tile * KT;
        const u16* kcur = kls[cur];
        const u16* vcur = vls[cur];
        f32x4 sacc[4];
        #pragma unroll
        for (int nt = 0; nt < 4; ++nt) sacc[nt] = (f32x4){0,0,0,0};
        #pragma unroll
        for (int cc = 0; cc < 5; ++cc) {
            #pragma unroll
            for (int nt = 0; nt < 4; ++nt) {
                bf16x8 bk = *(const bf16x8*)(kcur + (((cc * 4 + quad) * 64) + nt * 16 + l16) * 8);
                sacc[nt] = __builtin_amdgcn_mfma_f32_16x16x32_bf16(aq[cc], bk, sacc[nt], 0, 0, 0);
            }
        }
        #pragma unroll
        for (int nt = 0; nt < 4; ++nt) {
            int keyg = kb0 + nt * 16 + l16;
            bool ok = keyg < NTOKS;
            #pragma unroll
            for (int rr = 0; rr < 4; ++rr) {
                float p = ok ? __expf(sacc[nt][rr]) : 0.f;
                psum[rr] += p;
                pls[(w * 16 + quad * 4 + rr) * 72 + nt * 16 + l16] = f2b(p);
            }
        }
        #pragma unroll
        for (int kc = 0; kc < 2; ++kc) {
            bf16x8 ap = *(const bf16x8*)(pls + (w * 16 + l16) * 72 + kc * 32 + quad * 8);
            #pragma unroll
            for (int nt = 0; nt < 6; ++nt) {
                bf16x8 bv = *(const bf16x8*)(vcur + (((kc * 4 + quad) * 96) + nt * 16 + l16) * 8);
                accO[nt] = __builtin_amdgcn_mfma_f32_16x16x32_bf16(ap, bv, accO[nt], 0, 0, 0);
            }
        }
    }

    #pragma unroll
    for (int off = 1; off < 16; off <<= 1) {
        #pragma unroll
        for (int rr = 0; rr < 4; ++rr)
            psum[rr] += __shfl_xor(psum[rr], off);
    }
    const int sh = split * HEADS + h;
    if (l16 == 0) {
        #pragma unroll
        for (int rr = 0; rr < 4; ++rr) {
            int tok = q0 + w * 16 + quad * 4 + rr;
            if (tok < NTOKS)
                pl[(size_t)sh * NTOKS + tok] = psum[rr];
        }
    }
    #pragma unroll
    for (int rr = 0; rr < 4; ++rr) {
        int tok = q0 + w * 16 + quad * 4 + rr;
        if (tok >= NTOKS) continue;
        #pragma unroll
        for (int nt = 0; nt < 6; ++nt)
            pO[((size_t)sh * NTOKS + tok) * HD + nt * 16 + l16] = f2b(accO[nt][rr]);
    }
}

// ------- Kernel 4b: combine bf16 k-split partials + bf16 residual -> bf16 pre -------
__global__ __launch_bounds__(256) void combine(
    const u16* __restrict__ pO, const float* __restrict__ pl,
    const u16* __restrict__ qbb, u16* __restrict__ preb)
{
    int i = blockIdx.x * 256 + threadIdx.x;   // pair index: (tok, channel-pair)
    const int NP = NTOKS * 96;
    if (i >= NP) return;
    int tok = i / 96, dp = i - tok * 96;
    int d0 = dp * 2;
    int hh = d0 / HD, c0 = d0 - hh * HD;
    float l = 0.f, o0 = 0.f, o1 = 0.f;
    #pragma unroll
    for (int s = 0; s < NSPL; ++s) {
        l += pl[(size_t)(s * HEADS + hh) * NTOKS + tok];
        u32 pr = *(const u32*)(pO + ((size_t)(s * HEADS + hh) * NTOKS + tok) * HD + c0);
        o0 += b2f((u16)(pr & 0xffffu));
        o1 += b2f((u16)(pr >> 16));
    }
    float v0 = o0 / l, v1 = o1 / l;
    if (tok >= 1) {
        u32 qr = *(const u32*)(qbb + ((size_t)hh * NTOKS + tok) * HD + c0);
        v0 += b2f((u16)(qr & 0xffffu)) * INVS_;
        v1 += b2f((u16)(qr >> 16)) * INVS_;
    }
    u32 pack = (u32)f2b(v0) | ((u32)f2b(v1) << 16);
    *(u32*)(preb + (size_t)tok * DIM + d0) = pack;
}

extern "C" void kernel_launch(void* const* d_in, const int* in_sizes, int n_in,
                              void* d_out, int out_size, void* d_ws, size_t ws_size,
                              hipStream_t stream) {
    (void)in_sizes; (void)n_in; (void)out_size; (void)ws_size;
    const float* x      = (const float*)d_in[0];
    const float* qkv_w  = (const float*)d_in[1];
    const float* qkv_b  = (const float*)d_in[2];
    const float* proj_w = (const float*)d_in[3];
    const float* proj_b = (const float*)d_in[4];
    const float* pool_q = (const float*)d_in[5];
    const float* pool_k = (const float*)d_in[6];
    const float* pool_v = (const float*)d_in[7];
    const float* gq     = (const float*)d_in[8];
    const float* bq     = (const float*)d_in[9];
    const float* gk     = (const float*)d_in[10];
    const float* bk     = (const float*)d_in[11];
    const float* gv     = (const float*)d_in[12];
    const float* bv     = (const float*)d_in[13];
    const float* rel_h  = (const float*)d_in[14];
    const float* rel_w  = (const float*)d_in[15];
    const float* rel_t  = (const float*)d_in[16];

    char* p = (char*)d_ws;
    auto alloc = [&](size_t bytes) -> void* {
        void* r = (void*)p; p += (bytes + 255) & ~(size_t)255; return r;
    };
    u16*   qkvb = (u16*) alloc((size_t)NTOKS * 576 * 2);
    u16*   qbb = (u16*)  alloc((size_t)HEADS * NTOKS * HD * 2);
    u16*   kxb = (u16*)  alloc((size_t)HEADS * NTOKS * KCH * 2);
    u16*   vbb = (u16*)  alloc((size_t)HEADS * NTOKS * HD * 2);
    u16*   vbT = (u16*)  alloc((size_t)HEADS * HD * VT_LD * 2);
    float* bt  = (float*)alloc((size_t)HEADS * NSP * 8 * 4);
    float* bh  = (float*)alloc((size_t)HEADS * NSP * 28 * 4);
    float* bw  = (float*)alloc((size_t)HEADS * NSP * 28 * 4);
    u16*   pO  = (u16*)  alloc((size_t)NSPL * HEADS * NTOKS * HD * 2);
    float* pl  = (float*)alloc((size_t)NSPL * HEADS * NTOKS * 4);
    u16*   xb  = (u16*)  alloc((size_t)NTOKS * DIM * 2);
    u16*   qwb = (u16*)  alloc((size_t)576 * DIM * 2);
    u16*   pwb = (u16*)  alloc((size_t)DIM * DIM * 2);
    u16*   preb= (u16*)  alloc((size_t)NTOKS * DIM * 2);
    float* wT  = (float*)alloc((size_t)3 * 27 * 96 * 4);

    const int nx = NTOKS * DIM, nqw = 576 * DIM, npw = DIM * DIM;
    cvt_bf16<<<1024, 256, 0, stream>>>(x, xb, nx, qkv_w, qwb, nqw, proj_w, pwb, npw,
                                       pool_q, pool_k, pool_v, wT);
    gemm_bf16<<<dim3(QB3, 9), 256, 0, stream>>>(xb, qwb, qkv_b, nullptr, qkvb, NTOKS, 576);
    pool_ln3<<<HEADS * NSTRIP, 192, 0, stream>>>(
        qkvb, wT, gq, bq, gk, bk, gv, bv,
        rel_h, rel_w, rel_t, qbb, kxb, vbb, bt, bh, bw);
    vtrans<<<dim3((NTOKS + 127) / 128, HEADS), 256, 0, stream>>>(vbb, vbT);
    attn_mfma4<<<QB3 * 8, 256, 0, stream>>>(qbb, kxb, vbT, bt, bh, bw, pO, pl);
    combine<<<(NTOKS * 96 + 255) / 256, 256, 0, stream>>>(pO, pl, qbb, preb);
    gemm_bf16<<<dim3(QB3, 3), 256, 0, stream>>>(preb, pwb, proj_b, (float*)d_out, nullptr, NTOKS, 192);
}